// Round 3
// 443.755 us; speedup vs baseline: 1.0346x; 1.0346x over previous
//
#include <hip/hip_runtime.h>
#include <cstdint>

typedef unsigned short u16;
typedef __attribute__((ext_vector_type(8))) __bf16 bf16x8_t;
typedef __attribute__((ext_vector_type(4))) float f32x4_t;
typedef __attribute__((ext_vector_type(4))) uint32_t u32x4_t;

constexpr int Bn = 8, Tn = 4096, Dn = 1024, Hn = 1024;
constexpr int Mn = Bn * Tn;            // 32768 rows
constexpr int NC = 128, CL = Tn / NC;  // 128 chunks x 32 steps (chunk == one wave's rows)

__device__ __forceinline__ u16 f2bf(float f) {
  uint32_t u = __builtin_bit_cast(uint32_t, f);
  u += 0x7FFFu + ((u >> 16) & 1u);   // RNE; inputs finite
  return (u16)(u >> 16);
}

// single launch converts x, Wz, Wh to bf16
__global__ __launch_bounds__(256) void cvt_all(
    const float* __restrict__ x, const float* __restrict__ wz, const float* __restrict__ wh,
    u16* __restrict__ xb, u16* __restrict__ wzb, u16* __restrict__ whb) {
  int i = blockIdx.x * 256 + threadIdx.x;   // float4 index
  const float* s; u16* d; int off;
  if (i < 8388608)      { s = x;  d = xb;  off = i; }            // 32768*1024/4
  else if (i < 8650752) { s = wz; d = wzb; off = i - 8388608; }  // +1024*1024/4
  else                  { s = wh; d = whb; off = i - 8650752; }
  f32x4_t v = __builtin_nontemporal_load(&((const f32x4_t*)s)[off]);  // read-once
  ushort4 o;
  o.x = f2bf(v.x); o.y = f2bf(v.y); o.z = f2bf(v.z); o.w = f2bf(v.w);
  ((ushort4*)d)[off] = o;   // re-read soon by gemm: keep cached store
}

__device__ __forceinline__ void gl_lds16(const void* g, void* l) {
  __builtin_amdgcn_global_load_lds((const __attribute__((address_space(1))) void*)g,
                                   (__attribute__((address_space(3))) void*)l, 16u, 0, 0u);
}

__device__ __forceinline__ void gates(float kv, float tv, float& a, float& bb) {
  float e  = __expf(-kv);
  float rc = __builtin_amdgcn_rcpf(1.f + e);   // z = sigmoid(k)
  a = e * rc;                                  // 1-z, no cancellation
  float g = (tv >= 0.f) ? (tv + 0.5f)
                        : __builtin_amdgcn_rcpf(1.f + __expf(-tv));
  bb = rc * g;
}

// Fused dual NT GEMM + gate epilogue + per-chunk scan aggregates.
// Block: 128 m-rows x 64 h-cols, BOTH projections (Wz and Wh).
// Wave w owns m-rows [w*32, w*32+32) = exactly chunk tc = (mt&31)*4 + w.
// LDS is source-side swizzled: lane loads global k-chunk (l&3)^((l>>3)&3) so
// fragment ds_read_b128 spreads over all 8 bank-groups (2-way = free, was 8-way).
__global__ __launch_bounds__(256) void gemm_fused(
    const u16* __restrict__ A, const u16* __restrict__ Wz, const u16* __restrict__ Wh,
    const float* __restrict__ bz, const float* __restrict__ bh,
    uint32_t* __restrict__ gAB, float* __restrict__ Aagg, float* __restrict__ Bagg) {
  constexpr int K = 1024;
  const uint bid = blockIdx.x;
  const uint xcd = bid & 7;
  const uint seq = bid >> 3;
  const uint ht  = seq & 15;               // 16 h-tiles fastest per XCD (W L2-resident)
  const uint mt  = (seq >> 4) * 8 + xcd;   // 256 m-tiles
  const int m0 = mt * 128;
  const int h0 = ht * 64;

  __shared__ u16 lA[128 * 32];     // 8 KB
  __shared__ u16 lB[2][64 * 32];   // 2 x 4 KB (Wz, Wh)

  const int tid  = threadIdx.x;
  const int lane = tid & 63;
  const int wave = tid >> 6;

  // ---- staging addresses (swizzled source column) ----
  const int csA = (((lane & 3) ^ ((lane >> 3) & 3)) * 8);   // elem offset
  const int csB = (((tid  & 3) ^ ((tid  >> 3) & 3)) * 8);
  const u16* gA0 = A  + (size_t)(m0 + wave * 16 + (lane >> 2)) * K + csA;
  const u16* gBz = Wz + (size_t)(h0 + (tid >> 2)) * K + csB;
  const u16* gBh = Wh + (size_t)(h0 + (tid >> 2)) * K + csB;
  u16* lAw  = lA    + wave * 512;   // wave-uniform LDS dest (u16 units)
  u16* lBw0 = lB[0] + wave * 512;
  u16* lBw1 = lB[1] + wave * 512;

  // ---- fragment read offsets (deswizzled) ----
  const int fr   = lane & 15;
  const int KB   = lane >> 4;
  const int fcol = (KB ^ ((fr >> 1) & 3)) * 8;   // u16 elems within row

  f32x4_t az[2][4] = {}, ah[2][4] = {};

  for (int kt = 0; kt < K; kt += 32) {
    gl_lds16(gA0 + kt,                    lAw);
    gl_lds16(gA0 + kt + (size_t)64 * K,   lAw + 2048);   // rows +64
    gl_lds16(gBz + kt,                    lBw0);
    gl_lds16(gBh + kt,                    lBw1);
    __syncthreads();
    bf16x8_t af[2], bzf[4], bhf[4];
#pragma unroll
    for (int i = 0; i < 2; ++i)
      af[i] = *(const bf16x8_t*)&lA[(wave * 32 + i * 16 + fr) * 32 + fcol];
#pragma unroll
    for (int j = 0; j < 4; ++j) {
      bzf[j] = *(const bf16x8_t*)&lB[0][(j * 16 + fr) * 32 + fcol];
      bhf[j] = *(const bf16x8_t*)&lB[1][(j * 16 + fr) * 32 + fcol];
    }
#pragma unroll
    for (int i = 0; i < 2; ++i)
#pragma unroll
      for (int j = 0; j < 4; ++j) {
        az[i][j] = __builtin_amdgcn_mfma_f32_16x16x32_bf16(af[i], bzf[j], az[i][j], 0, 0, 0);
        ah[i][j] = __builtin_amdgcn_mfma_f32_16x16x32_bf16(af[i], bhf[j], ah[i][j], 0, 0, 0);
      }
    __syncthreads();
  }

  // ---- epilogue: gates + packed store + ordered affine composition ----
  // C/D: col = lane&15, row = (lane>>4)*4 + reg  [m89-verified]
  const int cr = (lane >> 4) * 4;   // q*4
  const int cc = lane & 15;
  const int b  = mt >> 5;                    // batch
  const int tc = (mt & 31) * 4 + wave;       // chunk id (32 t-rows)

#pragma unroll
  for (int j = 0; j < 4; ++j) {
    float bvz = bz[h0 + j * 16 + cc];
    float bvh = bh[h0 + j * 16 + cc];
    float Ai[2], Bi[2];
#pragma unroll
    for (int i = 0; i < 2; ++i) {
      float Al = 1.f, Bl = 0.f;
#pragma unroll
      for (int r = 0; r < 4; ++r) {
        float kv = az[i][j][r] + bvz;
        float tv = ah[i][j][r] + bvh;
        float a, bb;
        gates(kv, tv, a, bb);
        _Float16 a16 = (_Float16)a, b16 = (_Float16)bb;
        uint32_t pk = (uint32_t)__builtin_bit_cast(u16, a16) |
                      ((uint32_t)__builtin_bit_cast(u16, b16) << 16);
        // streaming write-once: keep it out of L2 so W/A tiles stay resident
        __builtin_nontemporal_store(
            pk, &gAB[(size_t)(m0 + wave * 32 + i * 16 + cr + r) * Hn + h0 + j * 16 + cc]);
        float ar = (float)a16, br = (float)b16;   // aggregate with the ROUNDED gates
        Al = Al * ar;
        Bl = fmaf(ar, Bl, br);
      }
      // ordered composition across lane-quads (rows ascend with q)
      float Ahi = __shfl_down(Al, 16), Bhi = __shfl_down(Bl, 16);
      float A2 = Ahi * Al;
      float B2 = fmaf(Ahi, Bl, Bhi);
      Ahi = __shfl_down(A2, 32); Bhi = __shfl_down(B2, 32);
      Ai[i] = Ahi * A2;
      Bi[i] = fmaf(Ahi, B2, Bhi);
    }
    float Aw = Ai[1] * Ai[0];                 // i=1 rows are later
    float Bw = fmaf(Ai[1], Bi[0], Bi[1]);
    if (lane < 16) {
      size_t ai = ((size_t)(b * NC + tc)) * Hn + h0 + j * 16 + lane;
      Aagg[ai] = Aw;
      Bagg[ai] = Bw;
    }
  }
}

// Phase B: serial scan of chunk aggregates -> carry per chunk. grid (16, B), 64 thr.
// carry MAY alias Aagg (read-before-write, same thread, same idx).
// Batched register prefetch (PF=16): the alias forbids the compiler from
// hoisting loads over the carry stores, which serialized 128 HBM-latency
// iterations (~100us). Reading a whole group before storing any of its
// slots is alias-safe (each thread only touches its own (b,h) column) and
// cuts the dependent-miss count 128 -> 8.
__global__ __launch_bounds__(64) void scan_phase_b(
    const float* Aagg, const float* __restrict__ Bagg, float* carry) {
  int h = blockIdx.x * 64 + threadIdx.x;
  int b = blockIdx.y;
  const size_t base = (size_t)b * NC * Hn + h;
  float state = 0.f;
  constexpr int PF = 16;
  float Av[PF], Bv[PF];
  for (int g = 0; g < NC; g += PF) {
#pragma unroll
    for (int u = 0; u < PF; ++u) {
      size_t idx = base + (size_t)(g + u) * Hn;
      Av[u] = Aagg[idx];
      Bv[u] = Bagg[idx];
    }
#pragma unroll
    for (int u = 0; u < PF; ++u) {
      size_t idx = base + (size_t)(g + u) * Hn;
      carry[idx] = state;
      state = fmaf(Av[u], state, Bv[u]);
    }
  }
}

// Phase C: pure fma stream over packed fp16 gates. grid (NC, B), 256 thr, 4 h/thr.
__global__ __launch_bounds__(256) void scan_phase_c(
    const uint32_t* __restrict__ gAB, const float* __restrict__ carry,
    float* __restrict__ out) {
  int h0 = threadIdx.x * 4;
  int c = blockIdx.x, b = blockIdx.y;
  f32x4_t hst = *(const f32x4_t*)(carry + ((size_t)(b * NC + c)) * Hn + h0);
  size_t base = ((size_t)b * Tn + (size_t)c * CL) * Hn + h0;
#pragma unroll 4
  for (int t = 0; t < CL; ++t) {
    size_t idx = base + (size_t)t * Hn;
    u32x4_t v = __builtin_nontemporal_load((const u32x4_t*)(gAB + idx));  // read-once
    uint32_t vv[4] = {v.x, v.y, v.z, v.w};
#pragma unroll
    for (int u = 0; u < 4; ++u) {
      float a = (float)__builtin_bit_cast(_Float16, (u16)(vv[u] & 0xFFFFu));
      float bb = (float)__builtin_bit_cast(_Float16, (u16)(vv[u] >> 16));
      hst[u] = fmaf(a, hst[u], bb);
    }
    __builtin_nontemporal_store(hst, (f32x4_t*)(out + idx));  // write-once
  }
}

extern "C" void kernel_launch(void* const* d_in, const int* in_sizes, int n_in,
                              void* d_out, int out_size, void* d_ws, size_t ws_size,
                              hipStream_t stream) {
  const float* x  = (const float*)d_in[0];
  const float* Wz = (const float*)d_in[1];
  const float* bz = (const float*)d_in[2];
  const float* Wh = (const float*)d_in[3];
  const float* bh = (const float*)d_in[4];
  float* out = (float*)d_out;

  // ws layout (bytes):
  //   xbf   64 MB @ 0
  //   wzbf   2 MB @ 67108864
  //   whbf   2 MB @ 69206016
  //   gAB  128 MB @ 71303168   ([M,H] u32 = fp16 a | b<<16)
  //   Aagg   4 MB @ 205520896  ([B,NC,H] fp32; carry aliases after phase B)
  //   Bagg   4 MB @ 209715200
  char* ws = (char*)d_ws;
  u16*      xbf   = (u16*)     (ws);
  u16*      wzbf  = (u16*)     (ws + 67108864);
  u16*      whbf  = (u16*)     (ws + 69206016);
  uint32_t* gAB   = (uint32_t*)(ws + 71303168);
  float*    Aagg  = (float*)   (ws + 205520896);
  float*    Bagg  = (float*)   (ws + 209715200);
  float*    carry = Aagg;   // safe alias

  cvt_all<<<dim3(34816), 256, 0, stream>>>(x, Wz, Wh, xbf, wzbf, whbf);
  gemm_fused<<<dim3(4096), 256, 0, stream>>>(xbf, wzbf, whbf, bz, bh, gAB, Aagg, Bagg);
  scan_phase_b<<<dim3(16, Bn), 64, 0, stream>>>(Aagg, Bagg, carry);
  scan_phase_c<<<dim3(NC, Bn), 256, 0, stream>>>(gAB, carry, out);
}